// Round 6
// baseline (383.722 us; speedup 1.0000x reference)
//
#include <hip/hip_runtime.h>

#define NBATCH  16
#define COLS_W  256                // columns per wave strip (64 lanes x float4)
#define NSTRIPS (1024 / COLS_W)    // 4
#define SEGROWS 16                 // rows per wave segment
#define NSEGS   (1024 / SEGROWS)   // 64
#define NWAVES  (NBATCH * NSTRIPS * NSEGS)  // 4096
#define NBLOCKS (NWAVES / 4)       // 1024 blocks x 4 waves = 4 blocks/CU, 16 waves/CU
#define NHIST   8                  // global histogram copies

__device__ __forceinline__ float gray3(float r, float g, float b) {
    return (r * 0.299f + g * 0.587f) + b * 0.114f;
}

// one gray row per lane: left-halo, 4 own columns, right-halo — ALL NAMED (no arrays:
// round-5's float[6] rows went to scratch, VGPR_Count=56, 3.4x collapse)
struct GrayRow { float l, c0, c1, c2, c3, r; };

__device__ __forceinline__ unsigned lbp8(float tl, float t, float tr,
                                         float l,  float c, float r,
                                         float bl, float bo, float br) {
    return (tr >= c ?   1u : 0u) |   // (y-1, x+1)
           (r  >= c ?   2u : 0u) |   // (y,   x+1)
           (br >= c ?   4u : 0u) |   // (y+1, x+1)
           (bo >= c ?   8u : 0u) |   // (y+1, x  )
           (bl >= c ?  16u : 0u) |   // (y+1, x-1)
           (l  >= c ?  32u : 0u) |   // (y,   x-1)
           (tl >= c ?  64u : 0u) |   // (y-1, x-1)
           (t  >= c ? 128u : 0u);    // (y-1, x  )
}

__global__ __launch_bounds__(256, 4) void lbp_hist_kernel(
        const float* __restrict__ img, unsigned* __restrict__ g_hist,
        float* __restrict__ out) {
    __shared__ unsigned s_hist[4][256];               // one copy per wave
    __shared__ float red[256];
    __shared__ int s_last;
    const int tid  = threadIdx.x;
    const int wv   = tid >> 6;
    const int lane = tid & 63;
    #pragma unroll
    for (int i = 0; i < 4; ++i) s_hist[i][tid] = 0u;
    __syncthreads();

    const int w     = blockIdx.x * 4 + wv;            // flat wave id 0..4095
    const int strip = w & (NSTRIPS - 1);              // adjacent waves -> adjacent strips
    const int seg   = (w >> 2) & (NSEGS - 1);
    const int b     = w >> 8;                         // 256 waves per batch image
    const int wx    = strip * COLS_W;
    const int x     = wx + 4 * lane;                  // first of this lane's 4 cols (16B aligned)
    const int y0    = seg * SEGROWS;
    const int ylast = y0 + SEGROWS;                   // deepest row consumed (y0+16)

    const float* R = img + (size_t)b * 3145728u;
    const float* G = R + 1048576;
    const float* B = R + 2097152;

    const bool hL  = (lane == 0);
    const bool hR  = (lane == 63);
    const int  hx  = hL ? (wx - 1) : (wx + COLS_W);   // halo column for edge lanes
    const bool hOk = (hL || hR) && ((unsigned)hx < 1024u);

    // issue: start float4 loads for one image row into NAMED float4 regs;
    // zero-fill OOB rows (SAME padding) and rows beyond [y0-1, ylast].
    auto issue = [&](int y, float4& rr, float4& gg, float4& bb,
                     float& hr2, float& hg2, float& hb2) {
        rr = gg = bb = make_float4(0.f, 0.f, 0.f, 0.f);
        hr2 = hg2 = hb2 = 0.f;
        if ((unsigned)y < 1024u && y <= ylast) {      // wave-uniform guard
            const int o = y << 10;
            rr = *(const float4*)(R + o + x);
            gg = *(const float4*)(G + o + x);
            bb = *(const float4*)(B + o + x);
            if (hOk) { hr2 = R[o + hx]; hg2 = G[o + hx]; hb2 = B[o + hx]; }
        }
    };
    // finish: gray-convert a landed row; returns by VALUE (SROA-friendly)
    auto finish = [&](const float4& rr, const float4& gg, const float4& bb,
                      float hr2, float hg2, float hb2) -> GrayRow {
        GrayRow o;
        o.c0 = gray3(rr.x, gg.x, bb.x);
        o.c1 = gray3(rr.y, gg.y, bb.y);
        o.c2 = gray3(rr.z, gg.z, bb.z);
        o.c3 = gray3(rr.w, gg.w, bb.w);
        const float hh = gray3(hr2, hg2, hb2);        // meaningful only on lanes 0/63
        const float lu = __shfl_up(o.c3, 1);          // lane-1's col x-1
        const float rd = __shfl_down(o.c0, 1);        // lane+1's col x+4
        o.l = hL ? hh : lu;                           // col x-1 (0-pad at image edge)
        o.r = hR ? hh : rd;                           // col x+4 (0-pad at image edge)
        return o;
    };

    // rolling 3x3 window rows (named structs) + depth-2 prefetch (named float4s)
    GrayRow r0, r1, r2;
    float4 p1r, p1g, p1b;  float p1hr, p1hg, p1hb;
    float4 p2r, p2g, p2b;  float p2hr, p2hg, p2hb;
    float4 nr,  ng,  nb;   float nhr,  nhg,  nhb;

    issue(y0 - 1, p1r, p1g, p1b, p1hr, p1hg, p1hb);
    r0 = finish(p1r, p1g, p1b, p1hr, p1hg, p1hb);     // row y0-1
    issue(y0,     p1r, p1g, p1b, p1hr, p1hg, p1hb);
    r1 = finish(p1r, p1g, p1b, p1hr, p1hg, p1hb);     // row y0
    issue(y0 + 1, p1r, p1g, p1b, p1hr, p1hg, p1hb);   // p1 = row y0+1 in flight
    issue(y0 + 2, p2r, p2g, p2b, p2hr, p2hg, p2hb);   // p2 = row y0+2 in flight

    unsigned cnt0 = 0u, cnt255 = 0u;

    #pragma unroll 4
    for (int y = y0; y < y0 + SEGROWS; ++y) {
        // keep 2 rows of loads in flight: issue y+3 before waiting on y+1
        issue(y + 3, nr, ng, nb, nhr, nhg, nhb);
        r2 = finish(p1r, p1g, p1b, p1hr, p1hg, p1hb); // row y+1

        const unsigned c0 = lbp8(r0.l,  r0.c0, r0.c1,  r1.l,  r1.c0, r1.c1,  r2.l,  r2.c0, r2.c1);
        const unsigned c1 = lbp8(r0.c0, r0.c1, r0.c2,  r1.c0, r1.c1, r1.c2,  r2.c0, r2.c1, r2.c2);
        const unsigned c2 = lbp8(r0.c1, r0.c2, r0.c3,  r1.c1, r1.c2, r1.c3,  r2.c1, r2.c2, r2.c3);
        const unsigned c3 = lbp8(r0.c2, r0.c3, r0.r,   r1.c2, r1.c3, r1.r,   r2.c2, r2.c3, r2.r);

        // hot bins (3x3 extremum, ~11% each on uniform data): ballot, no atomic
        cnt0   += (unsigned)__popcll(__ballot(c0 ==   0u));
        cnt0   += (unsigned)__popcll(__ballot(c1 ==   0u));
        cnt0   += (unsigned)__popcll(__ballot(c2 ==   0u));
        cnt0   += (unsigned)__popcll(__ballot(c3 ==   0u));
        cnt255 += (unsigned)__popcll(__ballot(c0 == 255u));
        cnt255 += (unsigned)__popcll(__ballot(c1 == 255u));
        cnt255 += (unsigned)__popcll(__ballot(c2 == 255u));
        cnt255 += (unsigned)__popcll(__ballot(c3 == 255u));
        if ((c0 - 1u) < 254u) atomicAdd(&s_hist[wv][c0], 1u);
        if ((c1 - 1u) < 254u) atomicAdd(&s_hist[wv][c1], 1u);
        if ((c2 - 1u) < 254u) atomicAdd(&s_hist[wv][c2], 1u);
        if ((c3 - 1u) < 254u) atomicAdd(&s_hist[wv][c3], 1u);

        r0 = r1; r1 = r2;                             // struct copies: pure v_movs
        p1r = p2r; p1g = p2g; p1b = p2b; p1hr = p2hr; p1hg = p2hg; p1hb = p2hb;
        p2r = nr;  p2g = ng;  p2b = nb;  p2hr = nhr;  p2hg = nhg;  p2hb = nhb;
    }

    if (lane == 0) {                                  // cnt0/cnt255 are wave-uniform
        atomicAdd(&s_hist[wv][0],   cnt0);
        atomicAdd(&s_hist[wv][255], cnt255);
    }
    __syncthreads();
    const unsigned total = s_hist[0][tid] + s_hist[1][tid] + s_hist[2][tid] + s_hist[3][tid];
    atomicAdd(&g_hist[((blockIdx.x & (NHIST - 1)) << 8) + tid], total);

    // ---- fused finalize: last block to finish reduces the copies ----
    __threadfence();                                  // release our flush
    if (tid == 0) {
        const unsigned rank = atomicAdd(&g_hist[NHIST * 256], 1u);
        s_last = (rank == NBLOCKS - 1) ? 1 : 0;
    }
    __syncthreads();
    if (s_last) {
        __threadfence();                              // acquire all flushes
        unsigned hv = 0u;
        #pragma unroll
        for (int c = 0; c < NHIST; ++c)
            hv += __hip_atomic_load(&g_hist[(c << 8) + tid],
                                    __ATOMIC_RELAXED, __HIP_MEMORY_SCOPE_AGENT);
        const float h = (float)hv;
        red[tid] = h;
        __syncthreads();
        #pragma unroll
        for (int s = 128; s > 0; s >>= 1) {
            if (tid < s) red[tid] += red[tid + s];
            __syncthreads();
        }
        const float mean = red[0] * (1.0f / 256.0f);
        __syncthreads();
        const float d = h - mean;
        red[tid] = d * d;
        __syncthreads();
        #pragma unroll
        for (int s = 128; s > 0; s >>= 1) {
            if (tid < s) red[tid] += red[tid + s];
            __syncthreads();
        }
        out[tid] = d / sqrtf(red[0] * (1.0f / 255.0f));
    }
}

extern "C" void kernel_launch(void* const* d_in, const int* in_sizes, int n_in,
                              void* d_out, int out_size, void* d_ws, size_t ws_size,
                              hipStream_t stream) {
    const float* img = (const float*)d_in[0];
    unsigned* g_hist = (unsigned*)d_ws;   // NHIST*256 bins + completion counter
    float* out = (float*)d_out;

    // zero hist copies + completion counter (graph-capture-safe, re-zeroed every replay)
    hipMemsetAsync(g_hist, 0, (NHIST * 256 + 4) * sizeof(unsigned), stream);
    lbp_hist_kernel<<<NBLOCKS, 256, 0, stream>>>(img, g_hist, out);
}

// Round 7
// 284.090 us; speedup vs baseline: 1.3507x; 1.3507x over previous
//
#include <hip/hip_runtime.h>

#define NBATCH  16
#define COLS_W  256                // columns per wave strip (64 lanes x float4)
#define NSTRIPS (1024 / COLS_W)    // 4
#define SEGROWS 16                 // rows per wave segment
#define NSEGS   (1024 / SEGROWS)   // 64
#define NWAVES  (NBATCH * NSTRIPS * NSEGS)  // 4096
#define NBLOCKS (NWAVES / 4)       // 1024 blocks x 4 waves = 4 blocks/CU, 16 waves/CU
#define NHIST   8                  // global histogram copies

__device__ __forceinline__ float gray3(float r, float g, float b) {
    return (r * 0.299f + g * 0.587f) + b * 0.114f;
}

__device__ __forceinline__ unsigned lbp8(float tl, float t, float tr,
                                         float l,  float c, float r,
                                         float bl, float bo, float br) {
    return (tr >= c ?   1u : 0u) |   // (y-1, x+1)
           (r  >= c ?   2u : 0u) |   // (y,   x+1)
           (br >= c ?   4u : 0u) |   // (y+1, x+1)
           (bo >= c ?   8u : 0u) |   // (y+1, x  )
           (bl >= c ?  16u : 0u) |   // (y+1, x-1)
           (l  >= c ?  32u : 0u) |   // (y,   x-1)
           (tl >= c ?  64u : 0u) |   // (y-1, x-1)
           (t  >= c ? 128u : 0u);    // (y-1, x  )
}

__global__ __launch_bounds__(256, 4) void lbp_hist_kernel(
        const float* __restrict__ img, unsigned* __restrict__ g_hist) {
    __shared__ unsigned s_hist[4][256];               // one copy per wave
    const int tid  = threadIdx.x;
    const int wv   = tid >> 6;
    const int lane = tid & 63;
    #pragma unroll
    for (int i = 0; i < 4; ++i) s_hist[i][tid] = 0u;
    __syncthreads();

    const int w     = blockIdx.x * 4 + wv;            // flat wave id 0..4095
    const int strip = w & (NSTRIPS - 1);              // adjacent waves -> adjacent strips
    const int seg   = (w >> 2) & (NSEGS - 1);
    const int b     = w >> 8;                         // 256 waves per batch image
    const int wx    = strip * COLS_W;
    const int x     = wx + 4 * lane;                  // first of this lane's 4 cols (16B aligned)
    const int y0    = seg * SEGROWS;
    const int ylast = y0 + SEGROWS;                   // deepest row consumed (y0+16)

    const float* R = img + (size_t)b * 3145728u;
    const float* G = R + 1048576;
    const float* B = R + 2097152;

    const bool hL  = (lane == 0);
    const bool hR  = (lane == 63);
    const int  hx  = hL ? (wx - 1) : (wx + COLS_W);   // halo column for edge lanes
    const bool hOk = (hL || hR) && ((unsigned)hx < 1024u);

    // issue: start float4 loads for one image row; zero-fill OOB rows (SAME padding)
    // and rows beyond [y0-1, ylast] (wave-uniform clamp). Same shape as proven r4 code.
    auto issue = [&](int y, float4& rr, float4& gg, float4& bb,
                     float& hr2, float& hg2, float& hb2) {
        rr = gg = bb = make_float4(0.f, 0.f, 0.f, 0.f);
        hr2 = hg2 = hb2 = 0.f;
        if ((unsigned)y < 1024u && y <= ylast) {
            const int o = y << 10;
            rr = *(const float4*)(R + o + x);
            gg = *(const float4*)(G + o + x);
            bb = *(const float4*)(B + o + x);
            if (hOk) { hr2 = R[o + hx]; hg2 = G[o + hx]; hb2 = B[o + hx]; }
        }
    };
    // finish: gray-convert a landed row into 6 NAMED scalars (l, c0..c3, r)
    auto finish = [&](const float4& rr, const float4& gg, const float4& bb,
                      float hr2, float hg2, float hb2,
                      float& l, float& c0, float& c1, float& c2, float& c3, float& r) {
        c0 = gray3(rr.x, gg.x, bb.x);
        c1 = gray3(rr.y, gg.y, bb.y);
        c2 = gray3(rr.z, gg.z, bb.z);
        c3 = gray3(rr.w, gg.w, bb.w);
        const float hh = gray3(hr2, hg2, hb2);        // meaningful only on lanes 0/63
        const float lu = __shfl_up(c3, 1);            // lane-1's col x-1
        const float rd = __shfl_down(c0, 1);          // lane+1's col x+4
        l = hL ? hh : lu;                             // col x-1 (0-pad at image edge)
        r = hR ? hh : rd;                             // col x+4 (0-pad at image edge)
    };

    // rolling 3x3 window rows: 18 individually-named floats (NO arrays, NO structs)
    float r0l, r0c0, r0c1, r0c2, r0c3, r0r;           // row y-1
    float r1l, r1c0, r1c1, r1c2, r1c3, r1r;           // row y
    float r2l, r2c0, r2c1, r2c2, r2c3, r2r;           // row y+1
    // depth-2 prefetch: p1 = next consumed row (y+1), p2 = row y+2
    float4 p1r, p1g, p1b;  float p1hr, p1hg, p1hb;
    float4 p2r, p2g, p2b;  float p2hr, p2hg, p2hb;
    float4 nr,  ng,  nb;   float nhr,  nhg,  nhb;

    issue(y0 - 1, p1r, p1g, p1b, p1hr, p1hg, p1hb);
    finish(p1r, p1g, p1b, p1hr, p1hg, p1hb, r0l, r0c0, r0c1, r0c2, r0c3, r0r);
    issue(y0,     p1r, p1g, p1b, p1hr, p1hg, p1hb);
    finish(p1r, p1g, p1b, p1hr, p1hg, p1hb, r1l, r1c0, r1c1, r1c2, r1c3, r1r);
    issue(y0 + 1, p1r, p1g, p1b, p1hr, p1hg, p1hb);   // p1 = row y0+1 in flight
    issue(y0 + 2, p2r, p2g, p2b, p2hr, p2hg, p2hb);   // p2 = row y0+2 in flight

    unsigned cnt0 = 0u, cnt255 = 0u;

    #pragma unroll 4
    for (int y = y0; y < y0 + SEGROWS; ++y) {
        // keep 2 rows of loads in flight: issue y+3 before waiting on y+1
        issue(y + 3, nr, ng, nb, nhr, nhg, nhb);
        finish(p1r, p1g, p1b, p1hr, p1hg, p1hb, r2l, r2c0, r2c1, r2c2, r2c3, r2r);

        const unsigned c0 = lbp8(r0l,  r0c0, r0c1,  r1l,  r1c0, r1c1,  r2l,  r2c0, r2c1);
        const unsigned c1 = lbp8(r0c0, r0c1, r0c2,  r1c0, r1c1, r1c2,  r2c0, r2c1, r2c2);
        const unsigned c2 = lbp8(r0c1, r0c2, r0c3,  r1c1, r1c2, r1c3,  r2c1, r2c2, r2c3);
        const unsigned c3 = lbp8(r0c2, r0c3, r0r,   r1c2, r1c3, r1r,   r2c2, r2c3, r2r);

        // hot bins (3x3 extremum, ~11% each on uniform data): ballot, no atomic
        cnt0   += (unsigned)__popcll(__ballot(c0 ==   0u));
        cnt0   += (unsigned)__popcll(__ballot(c1 ==   0u));
        cnt0   += (unsigned)__popcll(__ballot(c2 ==   0u));
        cnt0   += (unsigned)__popcll(__ballot(c3 ==   0u));
        cnt255 += (unsigned)__popcll(__ballot(c0 == 255u));
        cnt255 += (unsigned)__popcll(__ballot(c1 == 255u));
        cnt255 += (unsigned)__popcll(__ballot(c2 == 255u));
        cnt255 += (unsigned)__popcll(__ballot(c3 == 255u));
        if ((c0 - 1u) < 254u) atomicAdd(&s_hist[wv][c0], 1u);
        if ((c1 - 1u) < 254u) atomicAdd(&s_hist[wv][c1], 1u);
        if ((c2 - 1u) < 254u) atomicAdd(&s_hist[wv][c2], 1u);
        if ((c3 - 1u) < 254u) atomicAdd(&s_hist[wv][c3], 1u);

        r0l = r1l; r0c0 = r1c0; r0c1 = r1c1; r0c2 = r1c2; r0c3 = r1c3; r0r = r1r;
        r1l = r2l; r1c0 = r2c0; r1c1 = r2c1; r1c2 = r2c2; r1c3 = r2c3; r1r = r2r;
        p1r = p2r; p1g = p2g; p1b = p2b; p1hr = p2hr; p1hg = p2hg; p1hb = p2hb;
        p2r = nr;  p2g = ng;  p2b = nb;  p2hr = nhr;  p2hg = nhg;  p2hb = nhb;
    }

    if (lane == 0) {                                  // cnt0/cnt255 are wave-uniform
        atomicAdd(&s_hist[wv][0],   cnt0);
        atomicAdd(&s_hist[wv][255], cnt255);
    }
    __syncthreads();
    const unsigned total = s_hist[0][tid] + s_hist[1][tid] + s_hist[2][tid] + s_hist[3][tid];
    atomicAdd(&g_hist[((blockIdx.x & (NHIST - 1)) << 8) + tid], total);
}

__global__ __launch_bounds__(256) void lbp_finalize(
        const unsigned* __restrict__ g_hist, float* __restrict__ out) {
    __shared__ float red[256];
    const int i = threadIdx.x;
    unsigned hv = 0u;
    #pragma unroll
    for (int c = 0; c < NHIST; ++c) hv += g_hist[(c << 8) + i];
    const float h = (float)hv;
    red[i] = h;
    __syncthreads();
    #pragma unroll
    for (int s = 128; s > 0; s >>= 1) {
        if (i < s) red[i] += red[i + s];
        __syncthreads();
    }
    const float mean = red[0] * (1.0f / 256.0f);
    __syncthreads();
    const float d = h - mean;
    red[i] = d * d;
    __syncthreads();
    #pragma unroll
    for (int s = 128; s > 0; s >>= 1) {
        if (i < s) red[i] += red[i + s];
        __syncthreads();
    }
    const float stdv = sqrtf(red[0] * (1.0f / 255.0f));
    out[i] = d / stdv;
}

extern "C" void kernel_launch(void* const* d_in, const int* in_sizes, int n_in,
                              void* d_out, int out_size, void* d_ws, size_t ws_size,
                              hipStream_t stream) {
    const float* img = (const float*)d_in[0];
    unsigned* g_hist = (unsigned*)d_ws;   // NHIST * 256 * 4 = 8 KB scratch
    float* out = (float*)d_out;

    hipMemsetAsync(g_hist, 0, NHIST * 256 * sizeof(unsigned), stream);
    lbp_hist_kernel<<<NBLOCKS, 256, 0, stream>>>(img, g_hist);
    lbp_finalize<<<1, 256, 0, stream>>>(g_hist, out);
}